// Round 3
// baseline (621.761 us; speedup 1.0000x reference)
//
#include <hip/hip_runtime.h>
#include <hip/hip_bf16.h>

// Typed-relation MHA, MI355X.  B=2 L=2048 HID=512 NH=8 DH=64 T=3.
// Pipeline: conv/pack -> W transpose -> QKV gemm -> V-transpose -> qt gemm
//           -> flash attn (4-way K-split, in-block LDS merge) -> out gemm.

typedef __attribute__((ext_vector_type(4))) float f32x4;
typedef __attribute__((ext_vector_type(8))) short bf16x8;
typedef __attribute__((ext_vector_type(4))) unsigned short u16x4;

static __device__ __forceinline__ unsigned short f2bf(float x) {
  __hip_bfloat16 h = __float2bfloat16(x);
  return *reinterpret_cast<unsigned short*>(&h);
}
static __device__ __forceinline__ bf16x8 ld8(const unsigned short* p) {
  return *reinterpret_cast<const bf16x8*>(p);
}

// ---------------- P0a: convert query to bf16 + pack typed_ids to 2-bit ----------------
__global__ __launch_bounds__(256) void conv_pack(const float* __restrict__ query,
                                                 const int* __restrict__ tids,
                                                 unsigned short* __restrict__ q_bf,
                                                 unsigned char* __restrict__ tids2) {
  const int stride = gridDim.x * blockDim.x;
  const int tid = blockIdx.x * blockDim.x + threadIdx.x;
  for (int i = tid; i < 4096 * 512 / 4; i += stride) {
    const f32x4 v = *reinterpret_cast<const f32x4*>(query + (size_t)i * 4);
    u16x4 o;
#pragma unroll
    for (int j = 0; j < 4; j++) o[j] = f2bf(v[j]);
    *reinterpret_cast<u16x4*>(q_bf + (size_t)i * 4) = o;
  }
  for (int i = tid; i < 2 * 2048 * 512; i += stride) {
    const int4 v = *reinterpret_cast<const int4*>(tids + (size_t)i * 4);
    tids2[i] = (unsigned char)((v.x & 3) | ((v.y & 3) << 2) | ((v.z & 3) << 4) | ((v.w & 3) << 6));
  }
}

// ---------------- P0b: LDS-tiled W transposes (coalesced both sides) ----------------
// bid<256: Wq/Wk/Wv/Wo 64x64 tiles -> WT[3][n][k], WoT[n][k].  bid>=256: typed_weight.
__global__ __launch_bounds__(256) void w_transpose(
    const float* __restrict__ Wq, const float* __restrict__ Wk,
    const float* __restrict__ Wv, const float* __restrict__ Wo,
    const float* __restrict__ tw,
    unsigned short* __restrict__ WT_bf,     // [3][512 n][512 k]
    unsigned short* __restrict__ WoT_bf,    // [512 n][512 k]
    unsigned short* __restrict__ twT_bf) {  // [3][8][64 e][64 d]
  __shared__ float tile[64][65];
  const int bid = blockIdx.x;
  const int t = threadIdx.x;
  const float* src; unsigned short* dst; int lds_, ldd_;
  if (bid < 256) {
    const int m = bid >> 6, tl = bid & 63;
    const int k0 = (tl >> 3) * 64, n0 = (tl & 7) * 64;
    const float* W = (m == 0) ? Wq : (m == 1) ? Wk : (m == 2) ? Wv : Wo;
    src = W + k0 * 512 + n0;
    dst = ((m < 3) ? WT_bf + m * 512 * 512 : WoT_bf) + n0 * 512 + k0;
    lds_ = 512; ldd_ = 512;
  } else {
    const int idx = bid - 256;  // t*8+h, 0..23
    src = tw + idx * 4096; dst = twT_bf + idx * 4096;
    lds_ = 64; ldd_ = 64;
  }
#pragma unroll
  for (int p = 0; p < 4; p++) {
    const int i4 = t + p * 256;
    const int row = i4 >> 4, c4 = (i4 & 15) * 4;
    const f32x4 v = *reinterpret_cast<const f32x4*>(src + row * lds_ + c4);
#pragma unroll
    for (int j = 0; j < 4; j++) tile[row][c4 + j] = v[j];
  }
  __syncthreads();
#pragma unroll
  for (int p = 0; p < 2; p++) {
    const int i8 = t + p * 256;
    const int n = i8 >> 3, k8 = (i8 & 7) * 8;
    bf16x8 o;
#pragma unroll
    for (int j = 0; j < 8; j++) o[j] = (short)f2bf(tile[k8 + j][n]);
    *reinterpret_cast<bf16x8*>(dst + n * ldd_ + k8) = o;
  }
}

// ---------------- P1: fused QKV GEMM  C[4096,1536] ----------------
__global__ __launch_bounds__(256) void qkv_gemm(
    const unsigned short* __restrict__ Abf,  // query_bf [4096][512]
    const unsigned short* __restrict__ WT,   // [3][512 n][512 k]
    const float* __restrict__ bq, const float* __restrict__ bk, const float* __restrict__ bv,
    unsigned short* __restrict__ qh, unsigned short* __restrict__ kh,
    unsigned short* __restrict__ vh) {       // each [B,H,L,DH]
  const int m0 = blockIdx.x * 128;
  const int n0g = blockIdx.y * 64;
  const int mat = n0g >> 9;
  const int ncol0 = n0g & 511;
  const int h = ncol0 >> 6;
  const int wave = threadIdx.x >> 6, lane = threadIdx.x & 63;
  const int mw = wave >> 1, nw = wave & 1;
  const int lhi = lane >> 4, llo = lane & 15;
  const unsigned short* WTm = WT + mat * (512 * 512);
  f32x4 acc[4][2];
#pragma unroll
  for (int i = 0; i < 4; i++)
#pragma unroll
    for (int j = 0; j < 2; j++) acc[i][j] = (f32x4){0.f, 0.f, 0.f, 0.f};
  const int arow = m0 + mw * 64 + llo;
  const int brow = ncol0 + nw * 32 + llo;
  for (int k0 = 0; k0 < 512; k0 += 32) {
    const int kk = k0 + lhi * 8;
    bf16x8 a[4], b[2];
#pragma unroll
    for (int mf = 0; mf < 4; mf++) a[mf] = ld8(Abf + (arow + 16 * mf) * 512 + kk);
#pragma unroll
    for (int nf = 0; nf < 2; nf++) b[nf] = ld8(WTm + (brow + 16 * nf) * 512 + kk);
#pragma unroll
    for (int mf = 0; mf < 4; mf++)
#pragma unroll
      for (int nf = 0; nf < 2; nf++)
        acc[mf][nf] = __builtin_amdgcn_mfma_f32_16x16x32_bf16(a[mf], b[nf], acc[mf][nf], 0, 0, 0);
  }
  const float* bias = (mat == 0) ? bq : (mat == 1 ? bk : bv);
  unsigned short* dst = (mat == 0) ? qh : (mat == 1 ? kh : vh);
  const float scale = (mat == 0) ? 0.125f : 1.0f;
#pragma unroll
  for (int mf = 0; mf < 4; mf++) {
#pragma unroll
    for (int nf = 0; nf < 2; nf++) {
      const int d = nw * 32 + 16 * nf + llo;
      const float bv_ = bias[ncol0 + d];
#pragma unroll
      for (int r = 0; r < 4; r++) {
        const int row = m0 + mw * 64 + 16 * mf + lhi * 4 + r;
        const int bb = row >> 11, l = row & 2047;
        const float val = (acc[mf][nf][r] + bv_) * scale;
        dst[(((bb * 8 + h) * 2048) + l) * 64 + d] = f2bf(val);
      }
    }
  }
}

// ---------------- P2: V transpose [B,H,L,D] -> [B,H,D,L] ----------------
__global__ __launch_bounds__(256) void transpose_v(const unsigned short* __restrict__ vh,
                                                   unsigned short* __restrict__ vhT) {
  __shared__ unsigned short tile[64][65];
  const int bh = blockIdx.x;
  const int l0 = blockIdx.y * 64;
  const unsigned short* src = vh + bh * 2048 * 64;
  unsigned short* dst = vhT + bh * 64 * 2048;
  const int t = threadIdx.x;
#pragma unroll
  for (int p = 0; p < 2; p++) {
    const int idx = t + p * 256;
    const int l = idx >> 3, d0 = (idx & 7) * 8;
    bf16x8 v = ld8(src + (l0 + l) * 64 + d0);
#pragma unroll
    for (int j = 0; j < 8; j++) tile[l][d0 + j] = (unsigned short)v[j];
  }
  __syncthreads();
#pragma unroll
  for (int p = 0; p < 2; p++) {
    const int d = (t >> 3) + p * 32;
    const int ls = (t & 7) * 8;
    bf16x8 o;
#pragma unroll
    for (int j = 0; j < 8; j++) o[j] = (short)tile[ls + j][d];
    *reinterpret_cast<bf16x8*>(dst + d * 2048 + l0 + ls) = o;
  }
}

// ---------------- P3: qt = qh @ W_t -> [B,H,T,L,D] ----------------
__global__ __launch_bounds__(256) void qt_gemm(const unsigned short* __restrict__ qh,
                                               const unsigned short* __restrict__ twT,
                                               unsigned short* __restrict__ qt) {
  const int l0 = blockIdx.x * 128;
  const int bh = blockIdx.y;
  const int t = blockIdx.z;
  const int h = bh & 7;
  const int wave = threadIdx.x >> 6, lane = threadIdx.x & 63;
  const int lhi = lane >> 4, llo = lane & 15;
  const unsigned short* A = qh + bh * 2048 * 64;
  const unsigned short* Bt = twT + (t * 8 + h) * 64 * 64;
  const int r0 = l0 + wave * 32;
  f32x4 acc[2][4];
#pragma unroll
  for (int i = 0; i < 2; i++)
#pragma unroll
    for (int j = 0; j < 4; j++) acc[i][j] = (f32x4){0.f, 0.f, 0.f, 0.f};
  bf16x8 a[2][2], b[4][2];
#pragma unroll
  for (int mf = 0; mf < 2; mf++)
#pragma unroll
    for (int kk = 0; kk < 2; kk++)
      a[mf][kk] = ld8(A + (r0 + 16 * mf + llo) * 64 + kk * 32 + lhi * 8);
#pragma unroll
  for (int nf = 0; nf < 4; nf++)
#pragma unroll
    for (int kk = 0; kk < 2; kk++)
      b[nf][kk] = ld8(Bt + (16 * nf + llo) * 64 + kk * 32 + lhi * 8);
#pragma unroll
  for (int mf = 0; mf < 2; mf++)
#pragma unroll
    for (int nf = 0; nf < 4; nf++)
#pragma unroll
      for (int kk = 0; kk < 2; kk++)
        acc[mf][nf] = __builtin_amdgcn_mfma_f32_16x16x32_bf16(a[mf][kk], b[nf][kk], acc[mf][nf], 0, 0, 0);
  unsigned short* dst = qt + (bh * 3 + t) * 2048 * 64;
#pragma unroll
  for (int mf = 0; mf < 2; mf++)
#pragma unroll
    for (int nf = 0; nf < 4; nf++)
#pragma unroll
      for (int r = 0; r < 4; r++)
        dst[(r0 + 16 * mf + lhi * 4 + r) * 64 + 16 * nf + llo] = f2bf(acc[mf][nf][r]);
}

// ---------------- P4: flash attention, 4-way K-split ----------------
// grid 1024 1-D: bid&7 = (b, head-pair) -> pins each group's K/V to one XCD L2;
// bid>>3 = q-block.  Block 512 thr = 8 waves = 2 heads x 4 K-splits (512 cols each).
// In-block merge of the 4 splits via LDS tree (2 rounds).
__global__ __launch_bounds__(512, 8) void flash_attn(
    const unsigned short* __restrict__ qt,    // [B,H,3,L,D] (scaled)
    const unsigned short* __restrict__ kh,    // [B,H,L,D]
    const unsigned short* __restrict__ vhT,   // [B,H,D,L]
    const unsigned char* __restrict__ tids2,  // [B,L,L/4] 2-bit codes
    const float* __restrict__ bias,           // [B,L]
    unsigned short* __restrict__ xout) {      // [B,H,L,D]
  __shared__ unsigned char smem[16896];  // loop: pbuf 8x1280B; merge: obuf 16KB + ml 512B
  const int g = blockIdx.x & 7;
  const int q0 = (blockIdx.x >> 3) * 16;
  const int b = g >> 2, hgrp = g & 3;
  const int w = threadIdx.x >> 6;
  const int hp = w >> 2, s = w & 3;
  const int h = hgrp * 2 + hp;
  const int lane = threadIdx.x & 63;
  const int lhi = lane >> 4, llo = lane & 15;
  const int bh = b * 8 + h;
  const int kbase = s * 512;
  const unsigned short* khb = kh + bh * 2048 * 64;
  const unsigned short* vtb = vhT + bh * 64 * 2048;
  const unsigned char* tb2 = tids2 + b * 2048 * 512;
  const float* bb = bias + b * 2048;
  const float LOG2E = 1.4426950408889634f;
  const int sh = (llo & 3) * 2;

  unsigned short* pbuf = (unsigned short*)smem + w * 640;  // [16][40] shorts, per-wave
  float* obuf = (float*)smem;                               // [4 slots][64 lanes][16]
  float* mlbuf = (float*)(smem + 16384);                    // [4 slots][16 rows][2]

  bf16x8 qf[3][2];
#pragma unroll
  for (int t = 0; t < 3; t++)
#pragma unroll
    for (int kk = 0; kk < 2; kk++)
      qf[t][kk] = ld8(qt + ((size_t)(bh * 3 + t) * 2048 + q0 + llo) * 64 + kk * 32 + lhi * 8);

  int tofs[4];
#pragma unroll
  for (int r = 0; r < 4; r++) tofs[r] = (q0 + 4 * lhi + r) * 512 + (llo >> 2);

  f32x4 oacc[4];
#pragma unroll
  for (int i = 0; i < 4; i++) oacc[i] = (f32x4){0.f, 0.f, 0.f, 0.f};
  float mrow[4], lrow[4];
#pragma unroll
  for (int r = 0; r < 4; r++) { mrow[r] = -1e30f; lrow[r] = 0.f; }

  for (int kt = 0; kt < 512; kt += 32) {
    const int kcol = kbase + kt;
    const int koff = kcol >> 2;
    // typed-id codes first (coldest path)
    unsigned char tcode[2][4];
#pragma unroll
    for (int nf = 0; nf < 2; nf++)
#pragma unroll
      for (int r = 0; r < 4; r++) tcode[nf][r] = tb2[tofs[r] + koff + 4 * nf];
    bf16x8 kf[2][2];
#pragma unroll
    for (int nf = 0; nf < 2; nf++)
#pragma unroll
      for (int kk = 0; kk < 2; kk++)
        kf[nf][kk] = ld8(khb + (kcol + 16 * nf + llo) * 64 + kk * 32 + lhi * 8);

    f32x4 logit[2];
#pragma unroll
    for (int t = 0; t < 3; t++) {
      f32x4 s0 = (f32x4){0.f, 0.f, 0.f, 0.f}, s1 = (f32x4){0.f, 0.f, 0.f, 0.f};
      s0 = __builtin_amdgcn_mfma_f32_16x16x32_bf16(qf[t][0], kf[0][0], s0, 0, 0, 0);
      s0 = __builtin_amdgcn_mfma_f32_16x16x32_bf16(qf[t][1], kf[0][1], s0, 0, 0, 0);
      s1 = __builtin_amdgcn_mfma_f32_16x16x32_bf16(qf[t][0], kf[1][0], s1, 0, 0, 0);
      s1 = __builtin_amdgcn_mfma_f32_16x16x32_bf16(qf[t][1], kf[1][1], s1, 0, 0, 0);
      if (t == 0) { logit[0] = s0; logit[1] = s1; }
      else {
#pragma unroll
        for (int r = 0; r < 4; r++) {
          logit[0][r] = (((tcode[0][r] >> sh) & 3) == t) ? s0[r] : logit[0][r];
          logit[1][r] = (((tcode[1][r] >> sh) & 3) == t) ? s1[r] : logit[1][r];
        }
      }
    }
    const float b0 = bb[kcol + llo], b1 = bb[kcol + 16 + llo];
#pragma unroll
    for (int r = 0; r < 4; r++) { logit[0][r] += b0; logit[1][r] += b1; }

    float pmax[4], fr[4], rs[4];
#pragma unroll
    for (int r = 0; r < 4; r++) pmax[r] = fmaxf(logit[0][r], logit[1][r]);
#pragma unroll
    for (int xm = 1; xm < 16; xm <<= 1)
#pragma unroll
      for (int r = 0; r < 4; r++) pmax[r] = fmaxf(pmax[r], __shfl_xor(pmax[r], xm, 16));
#pragma unroll
    for (int r = 0; r < 4; r++) {
      const float mn = fmaxf(mrow[r], pmax[r]);
      fr[r] = exp2f((mrow[r] - mn) * LOG2E);
      mrow[r] = mn;
      rs[r] = 0.f;
    }
#pragma unroll
    for (int nf = 0; nf < 2; nf++)
#pragma unroll
      for (int r = 0; r < 4; r++) {
        const float p = exp2f((logit[nf][r] - mrow[r]) * LOG2E);
        logit[nf][r] = p;
        rs[r] += p;
      }
#pragma unroll
    for (int xm = 1; xm < 16; xm <<= 1)
#pragma unroll
      for (int r = 0; r < 4; r++) rs[r] += __shfl_xor(rs[r], xm, 16);
#pragma unroll
    for (int r = 0; r < 4; r++) lrow[r] = lrow[r] * fr[r] + rs[r];
#pragma unroll
    for (int nfd = 0; nfd < 4; nfd++)
#pragma unroll
      for (int r = 0; r < 4; r++) oacc[nfd][r] *= fr[r];

    // P (C-layout) -> per-wave LDS -> A-fragment layout (no barrier needed)
#pragma unroll
    for (int nf = 0; nf < 2; nf++)
#pragma unroll
      for (int r = 0; r < 4; r++)
        pbuf[(4 * lhi + r) * 40 + 16 * nf + llo] = f2bf(logit[nf][r]);
    const bf16x8 pa = *reinterpret_cast<const bf16x8*>(pbuf + llo * 40 + lhi * 8);
    bf16x8 vf[4];
#pragma unroll
    for (int nfd = 0; nfd < 4; nfd++)
      vf[nfd] = ld8(vtb + (16 * nfd + llo) * 2048 + kcol + lhi * 8);
#pragma unroll
    for (int nfd = 0; nfd < 4; nfd++)
      oacc[nfd] = __builtin_amdgcn_mfma_f32_16x16x32_bf16(pa, vf[nfd], oacc[nfd], 0, 0, 0);
  }

  // ---- merge 4 K-splits per head via LDS tree ----
  auto write_slot = [&](int slot) {
    float* o = obuf + (slot * 64 + lane) * 16;
#pragma unroll
    for (int nfd = 0; nfd < 4; nfd++)
      *reinterpret_cast<f32x4*>(o + nfd * 4) = oacc[nfd];
    if (llo == 0) {
#pragma unroll
      for (int r = 0; r < 4; r++) {
        mlbuf[slot * 32 + (4 * lhi + r) * 2] = mrow[r];
        mlbuf[slot * 32 + (4 * lhi + r) * 2 + 1] = lrow[r];
      }
    }
  };
  auto merge_slot = [&](int slot) {
    const float* o = obuf + (slot * 64 + lane) * 16;
#pragma unroll
    for (int r = 0; r < 4; r++) {
      const float mw = mlbuf[slot * 32 + (4 * lhi + r) * 2];
      const float lw = mlbuf[slot * 32 + (4 * lhi + r) * 2 + 1];
      const float M = fmaxf(mrow[r], mw);
      const float fa = exp2f((mrow[r] - M) * LOG2E);
      const float fb = exp2f((mw - M) * LOG2E);
      mrow[r] = M;
      lrow[r] = lrow[r] * fa + lw * fb;
#pragma unroll
      for (int nfd = 0; nfd < 4; nfd++)
        oacc[nfd][r] = oacc[nfd][r] * fa + o[nfd * 4 + r] * fb;
    }
  };
  __syncthreads();                       // done with pbuf everywhere
  if (s >= 2) write_slot(hp * 2 + (s - 2));
  __syncthreads();
  if (s < 2) merge_slot(hp * 2 + s);
  __syncthreads();
  if (s == 1) write_slot(hp);
  __syncthreads();
  if (s == 0) {
    merge_slot(hp);
    float inv[4];
#pragma unroll
    for (int r = 0; r < 4; r++) inv[r] = 1.f / lrow[r];
#pragma unroll
    for (int nfd = 0; nfd < 4; nfd++)
#pragma unroll
      for (int r = 0; r < 4; r++)
        xout[((size_t)bh * 2048 + q0 + 4 * lhi + r) * 64 + 16 * nfd + llo] = f2bf(oacc[nfd][r] * inv[r]);
  }
}

// ---------------- P5: out = x @ Wo + bo  (f32 out) ----------------
__global__ __launch_bounds__(256) void out_gemm(const unsigned short* __restrict__ xbf,
                                                const unsigned short* __restrict__ WoT,
                                                const float* __restrict__ bo,
                                                float* __restrict__ out) {
  const int m0 = blockIdx.x * 128;
  const int n0 = blockIdx.y * 64;
  const int wave = threadIdx.x >> 6, lane = threadIdx.x & 63;
  const int mw = wave >> 1, nw = wave & 1;
  const int lhi = lane >> 4, llo = lane & 15;
  f32x4 acc[4][2];
#pragma unroll
  for (int i = 0; i < 4; i++)
#pragma unroll
    for (int j = 0; j < 2; j++) acc[i][j] = (f32x4){0.f, 0.f, 0.f, 0.f};
  const int arow = m0 + mw * 64 + llo;
  const int bb = arow >> 11, l = arow & 2047;
  const int brow = n0 + nw * 32 + llo;
  for (int k0 = 0; k0 < 512; k0 += 32) {
    const int kk = k0 + lhi * 8;
    const int hk = kk >> 6, d0 = kk & 63;
    bf16x8 a[4], b[2];
#pragma unroll
    for (int mf = 0; mf < 4; mf++)
      a[mf] = ld8(xbf + ((bb * 8 + hk) * 2048 + l + 16 * mf) * 64 + d0);
#pragma unroll
    for (int nf = 0; nf < 2; nf++) b[nf] = ld8(WoT + (brow + 16 * nf) * 512 + kk);
#pragma unroll
    for (int mf = 0; mf < 4; mf++)
#pragma unroll
      for (int nf = 0; nf < 2; nf++)
        acc[mf][nf] = __builtin_amdgcn_mfma_f32_16x16x32_bf16(a[mf], b[nf], acc[mf][nf], 0, 0, 0);
  }
#pragma unroll
  for (int mf = 0; mf < 4; mf++)
#pragma unroll
    for (int nf = 0; nf < 2; nf++) {
      const int col = n0 + nw * 32 + 16 * nf + llo;
      const float bv_ = bo[col];
#pragma unroll
      for (int r = 0; r < 4; r++) {
        const int row = m0 + mw * 64 + 16 * mf + lhi * 4 + r;
        out[row * 512 + col] = acc[mf][nf][r] + bv_;
      }
    }
}

extern "C" void kernel_launch(void* const* d_in, const int* in_sizes, int n_in,
                              void* d_out, int out_size, void* d_ws, size_t ws_size,
                              hipStream_t stream) {
  const float* query = (const float*)d_in[0];
  const float* bias  = (const float*)d_in[1];
  const int*   tids  = (const int*)d_in[2];
  const float* Wq = (const float*)d_in[3];
  const float* bq = (const float*)d_in[4];
  const float* Wk = (const float*)d_in[5];
  const float* bk = (const float*)d_in[6];
  const float* Wv = (const float*)d_in[7];
  const float* bv = (const float*)d_in[8];
  const float* Wo = (const float*)d_in[9];
  const float* bo = (const float*)d_in[10];
  const float* tw = (const float*)d_in[11];
  float* out = (float*)d_out;

  char* ws = (char*)d_ws;
  size_t off = 0;
  auto take = [&](size_t bytes) { char* p = ws + off; off = (off + bytes + 255) & ~(size_t)255; return p; };
  unsigned short* q_bf   = (unsigned short*)take((size_t)4096 * 512 * 2);
  unsigned short* WT_bf  = (unsigned short*)take((size_t)3 * 512 * 512 * 2);
  unsigned short* WoT_bf = (unsigned short*)take((size_t)512 * 512 * 2);
  unsigned short* twT_bf = (unsigned short*)take((size_t)3 * 8 * 64 * 64 * 2);
  unsigned short* qh_bf  = (unsigned short*)take((size_t)2 * 8 * 2048 * 64 * 2);
  unsigned short* kh_bf  = (unsigned short*)take((size_t)2 * 8 * 2048 * 64 * 2);
  unsigned short* vh_bf  = (unsigned short*)take((size_t)2 * 8 * 2048 * 64 * 2);
  unsigned short* vhT_bf = (unsigned short*)take((size_t)2 * 8 * 64 * 2048 * 2);
  unsigned short* qt_bf  = (unsigned short*)take((size_t)2 * 8 * 3 * 2048 * 64 * 2);
  unsigned short* x_bf   = (unsigned short*)take((size_t)2 * 8 * 2048 * 64 * 2);
  unsigned char*  tids2  = (unsigned char*)take((size_t)2 * 2048 * 512);
  (void)ws_size; (void)in_sizes; (void)n_in; (void)out_size;

  conv_pack<<<dim3(1024), dim3(256), 0, stream>>>(query, tids, q_bf, tids2);
  w_transpose<<<dim3(280), dim3(256), 0, stream>>>(Wq, Wk, Wv, Wo, tw, WT_bf, WoT_bf, twT_bf);
  qkv_gemm<<<dim3(32, 24), dim3(256), 0, stream>>>(q_bf, WT_bf, bq, bk, bv, qh_bf, kh_bf, vh_bf);
  transpose_v<<<dim3(16, 32), dim3(256), 0, stream>>>(vh_bf, vhT_bf);
  qt_gemm<<<dim3(16, 16, 3), dim3(256), 0, stream>>>(qh_bf, twT_bf, qt_bf);
  flash_attn<<<dim3(1024), dim3(512), 0, stream>>>(qt_bf, kh_bf, vhT_bf, tids2, bias, x_bf);
  out_gemm<<<dim3(32, 8), dim3(256), 0, stream>>>(x_bf, WoT_bf, bo, out);
}

// Round 6
// 302.642 us; speedup vs baseline: 2.0544x; 2.0544x over previous
//
#include <hip/hip_runtime.h>
#include <hip/hip_bf16.h>

// Typed-relation MHA, MI355X.  B=2 L=2048 HID=512 NH=8 DH=64 T=3.
// Pipeline: conv/pack -> W transpose -> QKV gemm -> V-transpose -> qt gemm
//           -> flash attn (4-way K-split, in-block LDS merge) -> out gemm.
// R3 lesson: __launch_bounds__(512,8) capped VGPR at 64 -> allocator hit 32,
// spilled Q-frags+acc to scratch (899MB writes!). Use min_waves=4 (cap 128).

typedef __attribute__((ext_vector_type(4))) float f32x4;
typedef __attribute__((ext_vector_type(8))) short bf16x8;
typedef __attribute__((ext_vector_type(4))) unsigned short u16x4;

static __device__ __forceinline__ unsigned short f2bf(float x) {
  __hip_bfloat16 h = __float2bfloat16(x);
  return *reinterpret_cast<unsigned short*>(&h);
}
static __device__ __forceinline__ bf16x8 ld8(const unsigned short* p) {
  return *reinterpret_cast<const bf16x8*>(p);
}

// ---------------- P0a: convert query to bf16 + pack typed_ids to 2-bit ----------------
__global__ __launch_bounds__(256) void conv_pack(const float* __restrict__ query,
                                                 const int* __restrict__ tids,
                                                 unsigned short* __restrict__ q_bf,
                                                 unsigned char* __restrict__ tids2) {
  const int stride = gridDim.x * blockDim.x;
  const int tid = blockIdx.x * blockDim.x + threadIdx.x;
  for (int i = tid; i < 4096 * 512 / 4; i += stride) {
    const f32x4 v = *reinterpret_cast<const f32x4*>(query + (size_t)i * 4);
    u16x4 o;
#pragma unroll
    for (int j = 0; j < 4; j++) o[j] = f2bf(v[j]);
    *reinterpret_cast<u16x4*>(q_bf + (size_t)i * 4) = o;
  }
  for (int i = tid; i < 2 * 2048 * 512; i += stride) {
    const int4 v = *reinterpret_cast<const int4*>(tids + (size_t)i * 4);
    tids2[i] = (unsigned char)((v.x & 3) | ((v.y & 3) << 2) | ((v.z & 3) << 4) | ((v.w & 3) << 6));
  }
}

// ---------------- P0b: LDS-tiled W transposes (coalesced both sides) ----------------
__global__ __launch_bounds__(256) void w_transpose(
    const float* __restrict__ Wq, const float* __restrict__ Wk,
    const float* __restrict__ Wv, const float* __restrict__ Wo,
    const float* __restrict__ tw,
    unsigned short* __restrict__ WT_bf,     // [3][512 n][512 k]
    unsigned short* __restrict__ WoT_bf,    // [512 n][512 k]
    unsigned short* __restrict__ twT_bf) {  // [3][8][64 e][64 d]
  __shared__ float tile[64][65];
  const int bid = blockIdx.x;
  const int t = threadIdx.x;
  const float* src; unsigned short* dst; int lds_, ldd_;
  if (bid < 256) {
    const int m = bid >> 6, tl = bid & 63;
    const int k0 = (tl >> 3) * 64, n0 = (tl & 7) * 64;
    const float* W = (m == 0) ? Wq : (m == 1) ? Wk : (m == 2) ? Wv : Wo;
    src = W + k0 * 512 + n0;
    dst = ((m < 3) ? WT_bf + m * 512 * 512 : WoT_bf) + n0 * 512 + k0;
    lds_ = 512; ldd_ = 512;
  } else {
    const int idx = bid - 256;  // t*8+h, 0..23
    src = tw + idx * 4096; dst = twT_bf + idx * 4096;
    lds_ = 64; ldd_ = 64;
  }
#pragma unroll
  for (int p = 0; p < 4; p++) {
    const int i4 = t + p * 256;
    const int row = i4 >> 4, c4 = (i4 & 15) * 4;
    const f32x4 v = *reinterpret_cast<const f32x4*>(src + row * lds_ + c4);
#pragma unroll
    for (int j = 0; j < 4; j++) tile[row][c4 + j] = v[j];
  }
  __syncthreads();
#pragma unroll
  for (int p = 0; p < 2; p++) {
    const int i8 = t + p * 256;
    const int n = i8 >> 3, k8 = (i8 & 7) * 8;
    bf16x8 o;
#pragma unroll
    for (int j = 0; j < 8; j++) o[j] = (short)f2bf(tile[k8 + j][n]);
    *reinterpret_cast<bf16x8*>(dst + n * ldd_ + k8) = o;
  }
}

// ---------------- P1: fused QKV GEMM  C[4096,1536] ----------------
__global__ __launch_bounds__(256) void qkv_gemm(
    const unsigned short* __restrict__ Abf,  // query_bf [4096][512]
    const unsigned short* __restrict__ WT,   // [3][512 n][512 k]
    const float* __restrict__ bq, const float* __restrict__ bk, const float* __restrict__ bv,
    unsigned short* __restrict__ qh, unsigned short* __restrict__ kh,
    unsigned short* __restrict__ vh) {       // each [B,H,L,DH]
  const int m0 = blockIdx.x * 128;
  const int n0g = blockIdx.y * 64;
  const int mat = n0g >> 9;
  const int ncol0 = n0g & 511;
  const int h = ncol0 >> 6;
  const int wave = threadIdx.x >> 6, lane = threadIdx.x & 63;
  const int mw = wave >> 1, nw = wave & 1;
  const int lhi = lane >> 4, llo = lane & 15;
  const unsigned short* WTm = WT + mat * (512 * 512);
  f32x4 acc[4][2];
#pragma unroll
  for (int i = 0; i < 4; i++)
#pragma unroll
    for (int j = 0; j < 2; j++) acc[i][j] = (f32x4){0.f, 0.f, 0.f, 0.f};
  const int arow = m0 + mw * 64 + llo;
  const int brow = ncol0 + nw * 32 + llo;
  for (int k0 = 0; k0 < 512; k0 += 32) {
    const int kk = k0 + lhi * 8;
    bf16x8 a[4], b[2];
#pragma unroll
    for (int mf = 0; mf < 4; mf++) a[mf] = ld8(Abf + (arow + 16 * mf) * 512 + kk);
#pragma unroll
    for (int nf = 0; nf < 2; nf++) b[nf] = ld8(WTm + (brow + 16 * nf) * 512 + kk);
#pragma unroll
    for (int mf = 0; mf < 4; mf++)
#pragma unroll
      for (int nf = 0; nf < 2; nf++)
        acc[mf][nf] = __builtin_amdgcn_mfma_f32_16x16x32_bf16(a[mf], b[nf], acc[mf][nf], 0, 0, 0);
  }
  const float* bias = (mat == 0) ? bq : (mat == 1 ? bk : bv);
  unsigned short* dst = (mat == 0) ? qh : (mat == 1 ? kh : vh);
  const float scale = (mat == 0) ? 0.125f : 1.0f;
#pragma unroll
  for (int mf = 0; mf < 4; mf++) {
#pragma unroll
    for (int nf = 0; nf < 2; nf++) {
      const int d = nw * 32 + 16 * nf + llo;
      const float bv_ = bias[ncol0 + d];
#pragma unroll
      for (int r = 0; r < 4; r++) {
        const int row = m0 + mw * 64 + 16 * mf + lhi * 4 + r;
        const int bb = row >> 11, l = row & 2047;
        const float val = (acc[mf][nf][r] + bv_) * scale;
        dst[(((bb * 8 + h) * 2048) + l) * 64 + d] = f2bf(val);
      }
    }
  }
}

// ---------------- P2: V transpose [B,H,L,D] -> [B,H,D,L] ----------------
__global__ __launch_bounds__(256) void transpose_v(const unsigned short* __restrict__ vh,
                                                   unsigned short* __restrict__ vhT) {
  __shared__ unsigned short tile[64][65];
  const int bh = blockIdx.x;
  const int l0 = blockIdx.y * 64;
  const unsigned short* src = vh + bh * 2048 * 64;
  unsigned short* dst = vhT + bh * 64 * 2048;
  const int t = threadIdx.x;
#pragma unroll
  for (int p = 0; p < 2; p++) {
    const int idx = t + p * 256;
    const int l = idx >> 3, d0 = (idx & 7) * 8;
    bf16x8 v = ld8(src + (l0 + l) * 64 + d0);
#pragma unroll
    for (int j = 0; j < 8; j++) tile[l][d0 + j] = (unsigned short)v[j];
  }
  __syncthreads();
#pragma unroll
  for (int p = 0; p < 2; p++) {
    const int d = (t >> 3) + p * 32;
    const int ls = (t & 7) * 8;
    bf16x8 o;
#pragma unroll
    for (int j = 0; j < 8; j++) o[j] = (short)tile[ls + j][d];
    *reinterpret_cast<bf16x8*>(dst + d * 2048 + l0 + ls) = o;
  }
}

// ---------------- P3: qt = qh @ W_t -> [B,H,T,L,D] ----------------
__global__ __launch_bounds__(256) void qt_gemm(const unsigned short* __restrict__ qh,
                                               const unsigned short* __restrict__ twT,
                                               unsigned short* __restrict__ qt) {
  const int l0 = blockIdx.x * 128;
  const int bh = blockIdx.y;
  const int t = blockIdx.z;
  const int h = bh & 7;
  const int wave = threadIdx.x >> 6, lane = threadIdx.x & 63;
  const int lhi = lane >> 4, llo = lane & 15;
  const unsigned short* A = qh + bh * 2048 * 64;
  const unsigned short* Bt = twT + (t * 8 + h) * 64 * 64;
  const int r0 = l0 + wave * 32;
  f32x4 acc[2][4];
#pragma unroll
  for (int i = 0; i < 2; i++)
#pragma unroll
    for (int j = 0; j < 4; j++) acc[i][j] = (f32x4){0.f, 0.f, 0.f, 0.f};
  bf16x8 a[2][2], b[4][2];
#pragma unroll
  for (int mf = 0; mf < 2; mf++)
#pragma unroll
    for (int kk = 0; kk < 2; kk++)
      a[mf][kk] = ld8(A + (r0 + 16 * mf + llo) * 64 + kk * 32 + lhi * 8);
#pragma unroll
  for (int nf = 0; nf < 4; nf++)
#pragma unroll
    for (int kk = 0; kk < 2; kk++)
      b[nf][kk] = ld8(Bt + (16 * nf + llo) * 64 + kk * 32 + lhi * 8);
#pragma unroll
  for (int mf = 0; mf < 2; mf++)
#pragma unroll
    for (int nf = 0; nf < 4; nf++)
#pragma unroll
      for (int kk = 0; kk < 2; kk++)
        acc[mf][nf] = __builtin_amdgcn_mfma_f32_16x16x32_bf16(a[mf][kk], b[nf][kk], acc[mf][nf], 0, 0, 0);
  unsigned short* dst = qt + (bh * 3 + t) * 2048 * 64;
#pragma unroll
  for (int mf = 0; mf < 2; mf++)
#pragma unroll
    for (int nf = 0; nf < 4; nf++)
#pragma unroll
      for (int r = 0; r < 4; r++)
        dst[(r0 + 16 * mf + lhi * 4 + r) * 64 + 16 * nf + llo] = f2bf(acc[mf][nf][r]);
}

// ---------------- P4: flash attention, 4-way K-split ----------------
// grid 1024 1-D: bid&7 = (b, head-pair) -> pins each group's K/V to one XCD L2;
// bid>>3 = q-block.  Block 512 thr = 8 waves = 2 heads x 4 K-splits (512 cols each).
// In-block merge of the 4 splits via LDS tree (2 rounds).
// min_waves=4 (VGPR cap 128): kernel needs ~100 VGPR; cap 64 spilled (R3).
__global__ __launch_bounds__(512, 4) void flash_attn(
    const unsigned short* __restrict__ qt,    // [B,H,3,L,D] (scaled)
    const unsigned short* __restrict__ kh,    // [B,H,L,D]
    const unsigned short* __restrict__ vhT,   // [B,H,D,L]
    const unsigned char* __restrict__ tids2,  // [B,L,L/4] 2-bit codes
    const float* __restrict__ bias,           // [B,L]
    unsigned short* __restrict__ xout) {      // [B,H,L,D]
  __shared__ unsigned char smem[16896];  // loop: pbuf 8x1280B; merge: obuf 16KB + ml 512B
  const int g = blockIdx.x & 7;
  const int q0 = (blockIdx.x >> 3) * 16;
  const int b = g >> 2, hgrp = g & 3;
  const int w = threadIdx.x >> 6;
  const int hp = w >> 2, s = w & 3;
  const int h = hgrp * 2 + hp;
  const int lane = threadIdx.x & 63;
  const int lhi = lane >> 4, llo = lane & 15;
  const int bh = b * 8 + h;
  const int kbase = s * 512;
  const unsigned short* khb = kh + bh * 2048 * 64;
  const unsigned short* vtb = vhT + bh * 64 * 2048;
  const unsigned char* tb2 = tids2 + b * 2048 * 512;
  const float* bb = bias + b * 2048;
  const float LOG2E = 1.4426950408889634f;
  const int sh = (llo & 3) * 2;

  unsigned short* pbuf = (unsigned short*)smem + w * 640;  // [16][40] shorts, per-wave
  float* obuf = (float*)smem;                               // [4 slots][64 lanes][16]
  float* mlbuf = (float*)(smem + 16384);                    // [4 slots][16 rows][2]

  bf16x8 qf[3][2];
#pragma unroll
  for (int t = 0; t < 3; t++)
#pragma unroll
    for (int kk = 0; kk < 2; kk++)
      qf[t][kk] = ld8(qt + ((size_t)(bh * 3 + t) * 2048 + q0 + llo) * 64 + kk * 32 + lhi * 8);

  int tofs[4];
#pragma unroll
  for (int r = 0; r < 4; r++) tofs[r] = (q0 + 4 * lhi + r) * 512 + (llo >> 2);

  f32x4 oacc[4];
#pragma unroll
  for (int i = 0; i < 4; i++) oacc[i] = (f32x4){0.f, 0.f, 0.f, 0.f};
  float mrow[4], lrow[4];
#pragma unroll
  for (int r = 0; r < 4; r++) { mrow[r] = -1e30f; lrow[r] = 0.f; }

  for (int kt = 0; kt < 512; kt += 32) {
    const int kcol = kbase + kt;
    const int koff = kcol >> 2;
    unsigned char tcode[2][4];
#pragma unroll
    for (int nf = 0; nf < 2; nf++)
#pragma unroll
      for (int r = 0; r < 4; r++) tcode[nf][r] = tb2[tofs[r] + koff + 4 * nf];
    bf16x8 kf[2][2];
#pragma unroll
    for (int nf = 0; nf < 2; nf++)
#pragma unroll
      for (int kk = 0; kk < 2; kk++)
        kf[nf][kk] = ld8(khb + (kcol + 16 * nf + llo) * 64 + kk * 32 + lhi * 8);

    f32x4 logit[2];
#pragma unroll
    for (int t = 0; t < 3; t++) {
      f32x4 s0 = (f32x4){0.f, 0.f, 0.f, 0.f}, s1 = (f32x4){0.f, 0.f, 0.f, 0.f};
      s0 = __builtin_amdgcn_mfma_f32_16x16x32_bf16(qf[t][0], kf[0][0], s0, 0, 0, 0);
      s0 = __builtin_amdgcn_mfma_f32_16x16x32_bf16(qf[t][1], kf[0][1], s0, 0, 0, 0);
      s1 = __builtin_amdgcn_mfma_f32_16x16x32_bf16(qf[t][0], kf[1][0], s1, 0, 0, 0);
      s1 = __builtin_amdgcn_mfma_f32_16x16x32_bf16(qf[t][1], kf[1][1], s1, 0, 0, 0);
      if (t == 0) { logit[0] = s0; logit[1] = s1; }
      else {
#pragma unroll
        for (int r = 0; r < 4; r++) {
          logit[0][r] = (((tcode[0][r] >> sh) & 3) == t) ? s0[r] : logit[0][r];
          logit[1][r] = (((tcode[1][r] >> sh) & 3) == t) ? s1[r] : logit[1][r];
        }
      }
    }
    const float b0 = bb[kcol + llo], b1 = bb[kcol + 16 + llo];
#pragma unroll
    for (int r = 0; r < 4; r++) { logit[0][r] += b0; logit[1][r] += b1; }

    float pmax[4], fr[4], rs[4];
#pragma unroll
    for (int r = 0; r < 4; r++) pmax[r] = fmaxf(logit[0][r], logit[1][r]);
#pragma unroll
    for (int xm = 1; xm < 16; xm <<= 1)
#pragma unroll
      for (int r = 0; r < 4; r++) pmax[r] = fmaxf(pmax[r], __shfl_xor(pmax[r], xm, 16));
#pragma unroll
    for (int r = 0; r < 4; r++) {
      const float mn = fmaxf(mrow[r], pmax[r]);
      fr[r] = exp2f((mrow[r] - mn) * LOG2E);
      mrow[r] = mn;
      rs[r] = 0.f;
    }
#pragma unroll
    for (int nf = 0; nf < 2; nf++)
#pragma unroll
      for (int r = 0; r < 4; r++) {
        const float p = exp2f((logit[nf][r] - mrow[r]) * LOG2E);
        logit[nf][r] = p;
        rs[r] += p;
      }
#pragma unroll
    for (int xm = 1; xm < 16; xm <<= 1)
#pragma unroll
      for (int r = 0; r < 4; r++) rs[r] += __shfl_xor(rs[r], xm, 16);
#pragma unroll
    for (int r = 0; r < 4; r++) lrow[r] = lrow[r] * fr[r] + rs[r];
#pragma unroll
    for (int nfd = 0; nfd < 4; nfd++)
#pragma unroll
      for (int r = 0; r < 4; r++) oacc[nfd][r] *= fr[r];

    // P (C-layout) -> per-wave LDS -> A-fragment layout (no barrier needed)
#pragma unroll
    for (int nf = 0; nf < 2; nf++)
#pragma unroll
      for (int r = 0; r < 4; r++)
        pbuf[(4 * lhi + r) * 40 + 16 * nf + llo] = f2bf(logit[nf][r]);
    const bf16x8 pa = *reinterpret_cast<const bf16x8*>(pbuf + llo * 40 + lhi * 8);
    bf16x8 vf[4];
#pragma unroll
    for (int nfd = 0; nfd < 4; nfd++)
      vf[nfd] = ld8(vtb + (16 * nfd + llo) * 2048 + kcol + lhi * 8);
#pragma unroll
    for (int nfd = 0; nfd < 4; nfd++)
      oacc[nfd] = __builtin_amdgcn_mfma_f32_16x16x32_bf16(pa, vf[nfd], oacc[nfd], 0, 0, 0);
  }

  // ---- merge 4 K-splits per head via LDS tree ----
  auto write_slot = [&](int slot) {
    float* o = obuf + (slot * 64 + lane) * 16;
#pragma unroll
    for (int nfd = 0; nfd < 4; nfd++)
      *reinterpret_cast<f32x4*>(o + nfd * 4) = oacc[nfd];
    if (llo == 0) {
#pragma unroll
      for (int r = 0; r < 4; r++) {
        mlbuf[slot * 32 + (4 * lhi + r) * 2] = mrow[r];
        mlbuf[slot * 32 + (4 * lhi + r) * 2 + 1] = lrow[r];
      }
    }
  };
  auto merge_slot = [&](int slot) {
    const float* o = obuf + (slot * 64 + lane) * 16;
#pragma unroll
    for (int r = 0; r < 4; r++) {
      const float mw = mlbuf[slot * 32 + (4 * lhi + r) * 2];
      const float lw = mlbuf[slot * 32 + (4 * lhi + r) * 2 + 1];
      const float M = fmaxf(mrow[r], mw);
      const float fa = exp2f((mrow[r] - M) * LOG2E);
      const float fb = exp2f((mw - M) * LOG2E);
      mrow[r] = M;
      lrow[r] = lrow[r] * fa + lw * fb;
#pragma unroll
      for (int nfd = 0; nfd < 4; nfd++)
        oacc[nfd][r] = oacc[nfd][r] * fa + o[nfd * 4 + r] * fb;
    }
  };
  __syncthreads();                       // done with pbuf everywhere
  if (s >= 2) write_slot(hp * 2 + (s - 2));
  __syncthreads();
  if (s < 2) merge_slot(hp * 2 + s);
  __syncthreads();
  if (s == 1) write_slot(hp);
  __syncthreads();
  if (s == 0) {
    merge_slot(hp);
    float inv[4];
#pragma unroll
    for (int r = 0; r < 4; r++) inv[r] = 1.f / lrow[r];
#pragma unroll
    for (int nfd = 0; nfd < 4; nfd++)
#pragma unroll
      for (int r = 0; r < 4; r++)
        xout[((size_t)bh * 2048 + q0 + 4 * lhi + r) * 64 + 16 * nfd + llo] = f2bf(oacc[nfd][r] * inv[r]);
  }
}

// ---------------- P5: out = x @ Wo + bo  (f32 out) ----------------
__global__ __launch_bounds__(256) void out_gemm(const unsigned short* __restrict__ xbf,
                                                const unsigned short* __restrict__ WoT,
                                                const float* __restrict__ bo,
                                                float* __restrict__ out) {
  const int m0 = blockIdx.x * 128;
  const int n0 = blockIdx.y * 64;
  const int wave = threadIdx.x >> 6, lane = threadIdx.x & 63;
  const int mw = wave >> 1, nw = wave & 1;
  const int lhi = lane >> 4, llo = lane & 15;
  f32x4 acc[4][2];
#pragma unroll
  for (int i = 0; i < 4; i++)
#pragma unroll
    for (int j = 0; j < 2; j++) acc[i][j] = (f32x4){0.f, 0.f, 0.f, 0.f};
  const int arow = m0 + mw * 64 + llo;
  const int bb = arow >> 11, l = arow & 2047;
  const int brow = n0 + nw * 32 + llo;
  for (int k0 = 0; k0 < 512; k0 += 32) {
    const int kk = k0 + lhi * 8;
    const int hk = kk >> 6, d0 = kk & 63;
    bf16x8 a[4], b[2];
#pragma unroll
    for (int mf = 0; mf < 4; mf++)
      a[mf] = ld8(xbf + ((bb * 8 + hk) * 2048 + l + 16 * mf) * 64 + d0);
#pragma unroll
    for (int nf = 0; nf < 2; nf++) b[nf] = ld8(WoT + (brow + 16 * nf) * 512 + kk);
#pragma unroll
    for (int mf = 0; mf < 4; mf++)
#pragma unroll
      for (int nf = 0; nf < 2; nf++)
        acc[mf][nf] = __builtin_amdgcn_mfma_f32_16x16x32_bf16(a[mf], b[nf], acc[mf][nf], 0, 0, 0);
  }
#pragma unroll
  for (int mf = 0; mf < 4; mf++)
#pragma unroll
    for (int nf = 0; nf < 2; nf++) {
      const int col = n0 + nw * 32 + 16 * nf + llo;
      const float bv_ = bo[col];
#pragma unroll
      for (int r = 0; r < 4; r++) {
        const int row = m0 + mw * 64 + 16 * mf + lhi * 4 + r;
        out[row * 512 + col] = acc[mf][nf][r] + bv_;
      }
    }
}

extern "C" void kernel_launch(void* const* d_in, const int* in_sizes, int n_in,
                              void* d_out, int out_size, void* d_ws, size_t ws_size,
                              hipStream_t stream) {
  const float* query = (const float*)d_in[0];
  const float* bias  = (const float*)d_in[1];
  const int*   tids  = (const int*)d_in[2];
  const float* Wq = (const float*)d_in[3];
  const float* bq = (const float*)d_in[4];
  const float* Wk = (const float*)d_in[5];
  const float* bk = (const float*)d_in[6];
  const float* Wv = (const float*)d_in[7];
  const float* bv = (const float*)d_in[8];
  const float* Wo = (const float*)d_in[9];
  const float* bo = (const float*)d_in[10];
  const float* tw = (const float*)d_in[11];
  float* out = (float*)d_out;

  char* ws = (char*)d_ws;
  size_t off = 0;
  auto take = [&](size_t bytes) { char* p = ws + off; off = (off + bytes + 255) & ~(size_t)255; return p; };
  unsigned short* q_bf   = (unsigned short*)take((size_t)4096 * 512 * 2);
  unsigned short* WT_bf  = (unsigned short*)take((size_t)3 * 512 * 512 * 2);
  unsigned short* WoT_bf = (unsigned short*)take((size_t)512 * 512 * 2);
  unsigned short* twT_bf = (unsigned short*)take((size_t)3 * 8 * 64 * 64 * 2);
  unsigned short* qh_bf  = (unsigned short*)take((size_t)2 * 8 * 2048 * 64 * 2);
  unsigned short* kh_bf  = (unsigned short*)take((size_t)2 * 8 * 2048 * 64 * 2);
  unsigned short* vh_bf  = (unsigned short*)take((size_t)2 * 8 * 2048 * 64 * 2);
  unsigned short* vhT_bf = (unsigned short*)take((size_t)2 * 8 * 64 * 2048 * 2);
  unsigned short* qt_bf  = (unsigned short*)take((size_t)2 * 8 * 3 * 2048 * 64 * 2);
  unsigned short* x_bf   = (unsigned short*)take((size_t)2 * 8 * 2048 * 64 * 2);
  unsigned char*  tids2  = (unsigned char*)take((size_t)2 * 2048 * 512);
  (void)ws_size; (void)in_sizes; (void)n_in; (void)out_size;

  conv_pack<<<dim3(1024), dim3(256), 0, stream>>>(query, tids, q_bf, tids2);
  w_transpose<<<dim3(280), dim3(256), 0, stream>>>(Wq, Wk, Wv, Wo, tw, WT_bf, WoT_bf, twT_bf);
  qkv_gemm<<<dim3(32, 24), dim3(256), 0, stream>>>(q_bf, WT_bf, bq, bk, bv, qh_bf, kh_bf, vh_bf);
  transpose_v<<<dim3(16, 32), dim3(256), 0, stream>>>(vh_bf, vhT_bf);
  qt_gemm<<<dim3(16, 16, 3), dim3(256), 0, stream>>>(qh_bf, twT_bf, qt_bf);
  flash_attn<<<dim3(1024), dim3(512), 0, stream>>>(qt_bf, kh_bf, vhT_bf, tids2, bias, x_bf);
  out_gemm<<<dim3(32, 8), dim3(256), 0, stream>>>(x_bf, WoT_bf, bo, out);
}